// Round 5
// baseline (1893.376 us; speedup 1.0000x reference)
//
#include <hip/hip_runtime.h>
#include <hip/hip_bf16.h>

#define Bsz 256
#define Ssz 512
#define Fsz 64
#define Hsz 128
#define NG  512   // 4*H
#define GR  16    // batch rows per block
#define CH  4     // steps per staged chunk

typedef unsigned short ushort_t;
typedef __attribute__((ext_vector_type(8))) short short8v;
typedef __attribute__((ext_vector_type(4))) float float4v;

__device__ __forceinline__ ushort_t f2bf(float f) {
  unsigned int b = __float_as_uint(f);
  return (ushort_t)((b + 0x7fffu + ((b >> 16) & 1u)) >> 16);
}
__device__ __forceinline__ float bf2f(ushort_t u) {
  return __uint_as_float(((unsigned int)u) << 16);
}
__device__ __forceinline__ float sigf(float v) { return 1.f / (1.f + __expf(-v)); }
__device__ __forceinline__ float tanhf_fast(float v) {
  float e = __expf(2.f * v);
  return 1.f - 2.f / (e + 1.f);
}
// raw barrier: drain LDS only, keep global loads in flight
__device__ __forceinline__ void bar_sync() {
  asm volatile("s_waitcnt lgkmcnt(0)" ::: "memory");
  __builtin_amdgcn_s_barrier();
  asm volatile("" ::: "memory");
}

// --- kernel 1: inv_denom[s] = 1 / (sum_{b,f} m[b,s,f] + 1e-5) ---
__global__ void denom_kernel(const float* __restrict__ m, float* __restrict__ inv_denom) {
  int s = blockIdx.x;
  int tid = threadIdx.x;
  const float4* mp = (const float4*)(m + ((size_t)tid * Ssz + s) * Fsz);
  float sum = 0.f;
#pragma unroll
  for (int i = 0; i < Fsz / 4; ++i) {
    float4 v = mp[i];
    sum += v.x + v.y + v.z + v.w;
  }
  for (int off = 32; off > 0; off >>= 1) sum += __shfl_xor(sum, off);
  __shared__ float red[4];
  if ((tid & 63) == 0) red[tid >> 6] = sum;
  __syncthreads();
  if (tid == 0) {
    float tot = red[0] + red[1] + red[2] + red[3];
    inv_denom[s] = 1.0f / (tot + 1e-5f);
  }
}

// --- kernel 2: pack [Wih | Whh] into bf16 MFMA B-fragments (validated r2-r4) ---
__global__ void pack_kernel(const float* __restrict__ Wih, const float* __restrict__ Whh,
                            ushort_t* __restrict__ Wpk) {
  int g = blockIdx.x * blockDim.x + threadIdx.x;   // 0..16383
  if (g >= 16384) return;
  int lane = g & 63, nt = (g >> 6) & 31, kt = g >> 11;
  int jout = nt * 16 + (lane & 15);
  int kbase = kt * 32 + ((lane >> 4) << 3);
  ushort_t* dst = Wpk + (size_t)g * 8;
#pragma unroll
  for (int j = 0; j < 8; ++j) {
    int k = kbase + j;
    float w = (k < 128) ? Wih[jout * 128 + k] : Whh[jout * 128 + (k - 128)];
    dst[j] = f2bf(w);
  }
}

// --- kernel 3: gamma_h precompute (validated r3/r4) ---
__global__ void gh_kernel(const float* __restrict__ t, const float* __restrict__ Wdh,
                          const float* __restrict__ bdh, ushort_t* __restrict__ gh) {
  const int tid = threadIdx.x;
  const int lane = tid & 63, wv = tid >> 6;
  const int row0 = blockIdx.x * 64;
  __shared__ __align__(16) ushort_t st[64][72];
  __shared__ __align__(16) ushort_t sO[64][136];
  __shared__ float sbdh[128];
  if (tid < 128) sbdh[tid] = bdh[tid];
  short8v Bf[2][8];
#pragma unroll
  for (int kt = 0; kt < 2; ++kt)
#pragma unroll
    for (int nt = 0; nt < 8; ++nt) {
      int col = nt * 16 + (lane & 15);
      int k0 = kt * 32 + ((lane >> 4) << 3);
      float4 wa = *(const float4*)(Wdh + col * 64 + k0);
      float4 wb = *(const float4*)(Wdh + col * 64 + k0 + 4);
      short8v bb;
      bb[0] = (short)f2bf(wa.x); bb[1] = (short)f2bf(wa.y);
      bb[2] = (short)f2bf(wa.z); bb[3] = (short)f2bf(wa.w);
      bb[4] = (short)f2bf(wb.x); bb[5] = (short)f2bf(wb.y);
      bb[6] = (short)f2bf(wb.z); bb[7] = (short)f2bf(wb.w);
      Bf[kt][nt] = bb;
    }
  const float* tb = t + (size_t)row0 * 64;
  {
    int r = tid >> 2, c0 = (tid & 3) * 16;
#pragma unroll
    for (int q = 0; q < 4; ++q) {
      float4 v = *(const float4*)(tb + r * 64 + c0 + q * 4);
      st[r][c0 + q * 4 + 0] = f2bf(v.x);
      st[r][c0 + q * 4 + 1] = f2bf(v.y);
      st[r][c0 + q * 4 + 2] = f2bf(v.z);
      st[r][c0 + q * 4 + 3] = f2bf(v.w);
    }
  }
  __syncthreads();
  float4v acc[8] = {};
#pragma unroll
  for (int kt = 0; kt < 2; ++kt) {
    int r = wv * 16 + (lane & 15);
    int k0 = kt * 32 + ((lane >> 4) << 3);
    short8v a = *(const short8v*)&st[r][k0];
#pragma unroll
    for (int nt = 0; nt < 8; ++nt)
      acc[nt] = __builtin_amdgcn_mfma_f32_16x16x32_bf16(a, Bf[kt][nt], acc[nt], 0, 0, 0);
  }
#pragma unroll
  for (int nt = 0; nt < 8; ++nt)
#pragma unroll
    for (int rr = 0; rr < 4; ++rr) {
      int col = nt * 16 + (lane & 15);
      int row = wv * 16 + ((lane >> 4) << 2) + rr;
      float v = acc[nt][rr] + sbdh[col];
      sO[row][col] = f2bf(__expf(-fmaxf(0.f, v)));
    }
  __syncthreads();
  {
    int r = tid >> 2, c0 = (tid & 3) * 32;
    const uint4* src = (const uint4*)&sO[r][c0];
    uint4* dst = (uint4*)(gh + (size_t)(row0 + r) * 128 + c0);
#pragma unroll
    for (int q = 0; q < 4; ++q) dst[q] = src[q];
  }
}

// --- kernel 4: beta precompute (validated r3/r4) ---
__global__ void beta_kernel(const float* __restrict__ t, const float* __restrict__ m,
                            const float* __restrict__ Wdm, const float* __restrict__ bdm,
                            const float* __restrict__ Wwc, const float* __restrict__ bwc,
                            ushort_t* __restrict__ beta) {
  const int tid = threadIdx.x;
  const int lane = tid & 63, wv = tid >> 6;
  const int row0 = blockIdx.x * 64;
  __shared__ __align__(16) ushort_t sA[64][136];
  __shared__ __align__(16) ushort_t sO[64][72];
  __shared__ float sdw[64], sbd[64], sbwc[64];
  if (tid < 64) {
    sdw[tid] = Wdm[tid * 64 + tid];
    sbd[tid] = bdm[tid];
    sbwc[tid] = bwc[tid];
  }
  short8v Bf[4][4];
#pragma unroll
  for (int kt = 0; kt < 4; ++kt)
#pragma unroll
    for (int nt = 0; nt < 4; ++nt) {
      int col = nt * 16 + (lane & 15);
      int k0 = kt * 32 + ((lane >> 4) << 3);
      float4 wa = *(const float4*)(Wwc + col * 128 + k0);
      float4 wb = *(const float4*)(Wwc + col * 128 + k0 + 4);
      short8v bb;
      bb[0] = (short)f2bf(wa.x); bb[1] = (short)f2bf(wa.y);
      bb[2] = (short)f2bf(wa.z); bb[3] = (short)f2bf(wa.w);
      bb[4] = (short)f2bf(wb.x); bb[5] = (short)f2bf(wb.y);
      bb[6] = (short)f2bf(wb.z); bb[7] = (short)f2bf(wb.w);
      Bf[kt][nt] = bb;
    }
  __syncthreads();
  {
    int r = tid >> 2, c0 = (tid & 3) * 16;
    const float* tb = t + (size_t)row0 * 64;
    const float* mb = m + (size_t)row0 * 64;
#pragma unroll
    for (int q = 0; q < 4; ++q) {
      float4 tv = *(const float4*)(tb + r * 64 + c0 + q * 4);
      float4 mv = *(const float4*)(mb + r * 64 + c0 + q * 4);
      int c = c0 + q * 4;
      sA[r][c + 0] = f2bf(__expf(-fmaxf(0.f, tv.x * sdw[c + 0] + sbd[c + 0])));
      sA[r][c + 1] = f2bf(__expf(-fmaxf(0.f, tv.y * sdw[c + 1] + sbd[c + 1])));
      sA[r][c + 2] = f2bf(__expf(-fmaxf(0.f, tv.z * sdw[c + 2] + sbd[c + 2])));
      sA[r][c + 3] = f2bf(__expf(-fmaxf(0.f, tv.w * sdw[c + 3] + sbd[c + 3])));
      sA[r][64 + c + 0] = f2bf(mv.x);
      sA[r][64 + c + 1] = f2bf(mv.y);
      sA[r][64 + c + 2] = f2bf(mv.z);
      sA[r][64 + c + 3] = f2bf(mv.w);
    }
  }
  __syncthreads();
  float4v acc[4] = {};
#pragma unroll
  for (int kt = 0; kt < 4; ++kt) {
    int r = wv * 16 + (lane & 15);
    int k0 = kt * 32 + ((lane >> 4) << 3);
    short8v a = *(const short8v*)&sA[r][k0];
#pragma unroll
    for (int nt = 0; nt < 4; ++nt)
      acc[nt] = __builtin_amdgcn_mfma_f32_16x16x32_bf16(a, Bf[kt][nt], acc[nt], 0, 0, 0);
  }
#pragma unroll
  for (int nt = 0; nt < 4; ++nt)
#pragma unroll
    for (int rr = 0; rr < 4; ++rr) {
      int col = nt * 16 + (lane & 15);
      int row = wv * 16 + ((lane >> 4) << 2) + rr;
      sO[row][col] = f2bf(acc[nt][rr] + sbwc[col]);
    }
  __syncthreads();
  {
    int r = tid >> 2, c0 = (tid & 3) * 16;
    const uint4* src = (const uint4*)&sO[r][c0];
    uint4* dst = (uint4*)(beta + (size_t)(row0 + r) * 64 + c0);
    dst[0] = src[0];
    dst[1] = src[1];
  }
}

// --- kernel 5: recurrence, 16 batch rows per block. 16 blocks x 512 threads. ---
// V LDS [16 rows][264] bf16; k: 0..63 cl_c, 64..127 ml, 128..255 decayed h.
// MFMA maps: A row = lane&15 (batch row), k = kt*32 + (lane>>4)*8 + j.
//            D col = lane&15 (out idx),  row = (lane>>4)*4 + reg (batch row).
__launch_bounds__(512, 1)
__global__ void rits_kernel(
    const float* __restrict__ x, const float* __restrict__ m,
    const float* __restrict__ Wtr, const float* __restrict__ btr,
    const float* __restrict__ Wfr, const float* __restrict__ bfr,
    const float* __restrict__ bih, const float* __restrict__ bhh,
    const ushort_t* __restrict__ Wpk, const float* __restrict__ inv_denom,
    const ushort_t* __restrict__ ghp, const ushort_t* __restrict__ betap,
    float* __restrict__ out_imp, float* __restrict__ out_loss)
{
  const int b0 = blockIdx.x * GR;
  const int tid = threadIdx.x;
  const int lane = tid & 63;
  const int wv = tid >> 6;
  const int l15 = lane & 15;
  const int kg = lane >> 4;

  __shared__ float sIdn[Ssz];
  __shared__ __align__(16) ushort_t sV[GR][264];
  __shared__ __align__(16) float    sXlh[GR][68];
  __shared__ __align__(16) ushort_t sXcF[GR][72];
  __shared__ __align__(16) float    sXb[2][CH][GR][68];
  __shared__ __align__(16) ushort_t sMb[2][CH][GR][72];
  __shared__ __align__(16) ushort_t sBb[2][CH][GR][72];
  __shared__ __align__(16) ushort_t sGb[2][CH][GR][136];
  __shared__ float sRed[8];

  // gates B-frags (nt = wv + 8n) + bias
  const short8v* wp = (const short8v*)Wpk;
  short8v Bf[8][4];
#pragma unroll
  for (int kt = 0; kt < 8; ++kt)
#pragma unroll
    for (int n = 0; n < 4; ++n)
      Bf[kt][n] = wp[((kt * 32 + wv + 8 * n) << 6) + lane];
  float gb[4];
#pragma unroll
  for (int n = 0; n < 4; ++n) {
    int j = (wv + 8 * n) * 16 + l15;
    gb[n] = bih[j] + bhh[j];
  }

  // union frags: waves 0-3: Wtr (nt=wv, 4 kt); waves 4-7: Wfr (nt=wv-4, 2 kt, diag 0)
  short8v uW[4];
  float btr_r = 0.f, bfr_r = 0.f;
  if (wv < 4) {
    const int col = wv * 16 + l15;
#pragma unroll
    for (int kt = 0; kt < 4; ++kt) {
      int k0 = kt * 32 + kg * 8;
      short8v bb;
#pragma unroll
      for (int j = 0; j < 8; ++j) bb[j] = (short)f2bf(Wtr[col * 128 + k0 + j]);
      uW[kt] = bb;
    }
    btr_r = btr[col];
  } else {
    const int col = (wv - 4) * 16 + l15;
#pragma unroll
    for (int kt = 0; kt < 2; ++kt) {
      int k0 = kt * 32 + kg * 8;
      short8v bb;
#pragma unroll
      for (int j = 0; j < 8; ++j) {
        int k = k0 + j;
        bb[j] = (k == col) ? (short)0 : (short)f2bf(Wfr[col * 64 + k]);
      }
      uW[kt] = bb;
    }
    uW[2] = uW[0]; uW[3] = uW[1];
    bfr_r = bfr[col];
  }

  // staging thread map (fixed per thread)
  const int sg2 = tid >> 7;            // step-in-chunk 0..3
  const int rg  = (tid >> 3) & 15;     // batch row 0..15
  const int fg8 = (tid & 7) * 8;       // feature group
  const int hg16 = (tid & 7) * 16;     // h group
  const float*    xbase = x     + (size_t)(b0 + rg) * Ssz * Fsz + sg2 * 64 + fg8;
  const float*    mbase = m     + (size_t)(b0 + rg) * Ssz * Fsz + sg2 * 64 + fg8;
  const ushort_t* bbase = betap + (size_t)(b0 + rg) * Ssz * Fsz + sg2 * 64 + fg8;
  const size_t    ghoff = (size_t)(b0 + rg) * Ssz * Hsz + hg16;
  float* op = out_imp + (size_t)b0 * Ssz * Fsz;

  // prologue: stage chunk 0 + init V + idn
  {
    float4 a = *(const float4*)xbase, b2 = *(const float4*)(xbase + 4);
    *(float4*)&sXb[0][sg2][rg][fg8]     = a;
    *(float4*)&sXb[0][sg2][rg][fg8 + 4] = b2;
    float4 ma = *(const float4*)mbase, mb2 = *(const float4*)(mbase + 4);
    uint4 mq;
    mq.x = (unsigned)f2bf(ma.x)  | ((unsigned)f2bf(ma.y)  << 16);
    mq.y = (unsigned)f2bf(ma.z)  | ((unsigned)f2bf(ma.w)  << 16);
    mq.z = (unsigned)f2bf(mb2.x) | ((unsigned)f2bf(mb2.y) << 16);
    mq.w = (unsigned)f2bf(mb2.z) | ((unsigned)f2bf(mb2.w) << 16);
    *(uint4*)&sMb[0][sg2][rg][fg8] = mq;
    if (sg2 == 0) *(uint4*)&sV[rg][64 + fg8] = mq;
    *(uint4*)&sBb[0][sg2][rg][fg8] = *(const uint4*)bbase;
    const ushort_t* gp_ = ghp + ghoff + (size_t)(sg2 + 1) * 128;
    *(uint4*)&sGb[0][sg2][rg][hg16]     = *(const uint4*)gp_;
    *(uint4*)&sGb[0][sg2][rg][hg16 + 8] = *(const uint4*)(gp_ + 8);
    // zero decayed-h region of V
    *(unsigned long long*)&sV[tid >> 5][128 + (tid & 31) * 4] = 0ULL;
    sIdn[tid] = inv_denom[tid];
  }
  __syncthreads();

  float lacc = 0.f;
  float c_reg[4] = {0.f, 0.f, 0.f, 0.f};
  float4 xr0, xr1, mr0, mr1;
  uint4 ber, gr0, gr1;

  const char* vrow = (const char*)sV + l15 * 528 + kg * 16;

#pragma unroll 4
  for (int s = 0; s < Ssz; ++s) {
    const int p = (s >> 2) & 1, sc = s & 3;
    const float idn = sIdn[s];

    // ---- issue next-chunk global loads (in flight across raw barriers) ----
    if (sc == 0 && s + CH < Ssz) {
      const int cs = s + CH;
      xr0 = *(const float4*)(xbase + cs * 64);
      xr1 = *(const float4*)(xbase + cs * 64 + 4);
      mr0 = *(const float4*)(mbase + cs * 64);
      mr1 = *(const float4*)(mbase + cs * 64 + 4);
      ber = *(const uint4*)(bbase + cs * 64);
      int st = cs + sg2 + 1; if (st > Ssz - 1) st = Ssz - 1;
      const ushort_t* gp_ = ghp + ghoff + (size_t)st * 128;
      gr0 = *(const uint4*)gp_;
      gr1 = *(const uint4*)(gp_ + 8);
    }

    // ================= P1 =================
    short8v ah0 = *(const short8v*)(vrow + 256);
    short8v ah1 = *(const short8v*)(vrow + 320);
    short8v ah2 = *(const short8v*)(vrow + 384);
    short8v ah3 = *(const short8v*)(vrow + 448);

    float4v acc[4];
#pragma unroll
    for (int n = 0; n < 4; ++n) acc[n] = (float4v){gb[n], gb[n], gb[n], gb[n]};

    if (wv < 4) {
#pragma unroll
      for (int n = 0; n < 4; ++n) {
        acc[n] = __builtin_amdgcn_mfma_f32_16x16x32_bf16(ah0, Bf[4][n], acc[n], 0, 0, 0);
        acc[n] = __builtin_amdgcn_mfma_f32_16x16x32_bf16(ah1, Bf[5][n], acc[n], 0, 0, 0);
      }
      float4v xacc = (float4v){0.f, 0.f, 0.f, 0.f};
      xacc = __builtin_amdgcn_mfma_f32_16x16x32_bf16(ah0, uW[0], xacc, 0, 0, 0);
      xacc = __builtin_amdgcn_mfma_f32_16x16x32_bf16(ah1, uW[1], xacc, 0, 0, 0);
      xacc = __builtin_amdgcn_mfma_f32_16x16x32_bf16(ah2, uW[2], xacc, 0, 0, 0);
      xacc = __builtin_amdgcn_mfma_f32_16x16x32_bf16(ah3, uW[3], xacc, 0, 0, 0);
      const int fc = wv * 16 + l15;
#pragma unroll
      for (int r = 0; r < 4; ++r) {
        const int row = kg * 4 + r;
        float xl = xacc[r] + btr_r;
        float xv = sXb[p][sc][row][fc];
        float mv = bf2f(sMb[p][sc][row][fc]);
        float xlc = mv * xv + (1.f - mv) * xl;
        float d = xv - xl;
        lacc += d * d * mv * idn;            // loss term 1
        sXlh[row][fc] = xl;
        sXcF[row][fc] = f2bf(xlc);
      }
    } else {
      short8v am0 = *(const short8v*)(vrow + 128);
      short8v am1 = *(const short8v*)(vrow + 192);
#pragma unroll
      for (int n = 0; n < 4; ++n) {
        acc[n] = __builtin_amdgcn_mfma_f32_16x16x32_bf16(am0, Bf[2][n], acc[n], 0, 0, 0);
        acc[n] = __builtin_amdgcn_mfma_f32_16x16x32_bf16(am1, Bf[3][n], acc[n], 0, 0, 0);
        acc[n] = __builtin_amdgcn_mfma_f32_16x16x32_bf16(ah0, Bf[4][n], acc[n], 0, 0, 0);
        acc[n] = __builtin_amdgcn_mfma_f32_16x16x32_bf16(ah1, Bf[5][n], acc[n], 0, 0, 0);
        acc[n] = __builtin_amdgcn_mfma_f32_16x16x32_bf16(ah2, Bf[6][n], acc[n], 0, 0, 0);
        acc[n] = __builtin_amdgcn_mfma_f32_16x16x32_bf16(ah3, Bf[7][n], acc[n], 0, 0, 0);
      }
    }
    bar_sync();

    // ================= P2 =================
    if (wv < 4) {
      short8v am0 = *(const short8v*)(vrow + 128);
      short8v am1 = *(const short8v*)(vrow + 192);
#pragma unroll
      for (int n = 0; n < 4; ++n) {
        acc[n] = __builtin_amdgcn_mfma_f32_16x16x32_bf16(am0, Bf[2][n], acc[n], 0, 0, 0);
        acc[n] = __builtin_amdgcn_mfma_f32_16x16x32_bf16(am1, Bf[3][n], acc[n], 0, 0, 0);
        acc[n] = __builtin_amdgcn_mfma_f32_16x16x32_bf16(ah2, Bf[6][n], acc[n], 0, 0, 0);
        acc[n] = __builtin_amdgcn_mfma_f32_16x16x32_bf16(ah3, Bf[7][n], acc[n], 0, 0, 0);
      }
    } else {
      const char* xrow = (const char*)sXcF + l15 * 144 + kg * 16;
      short8v ax0 = *(const short8v*)(xrow);
      short8v ax1 = *(const short8v*)(xrow + 64);
      float4v zacc = (float4v){0.f, 0.f, 0.f, 0.f};
      zacc = __builtin_amdgcn_mfma_f32_16x16x32_bf16(ax0, uW[0], zacc, 0, 0, 0);
      zacc = __builtin_amdgcn_mfma_f32_16x16x32_bf16(ax1, uW[1], zacc, 0, 0, 0);
      const int fc = (wv - 4) * 16 + l15;
#pragma unroll
      for (int r = 0; r < 4; ++r) {
        const int row = kg * 4 + r;
        float zl = zacc[r] + bfr_r;
        float xlh = sXlh[row][fc];
        float bev = bf2f(sBb[p][sc][row][fc]);
        float xv = sXb[p][sc][row][fc];
        float mv = bf2f(sMb[p][sc][row][fc]);
        float clh = bev * zl + (1.f - bev) * xlh;
        float d2 = xv - zl, d3 = xv - clh;
        lacc += (d2 * d2 + d3 * d3) * mv * idn;   // loss terms 2+3
        float clc = mv * xv + (1.f - mv) * clh;
        sV[row][fc] = f2bf(clc);
        op[(size_t)row * Ssz * Fsz + s * 64 + fc] = clc;
      }
    }
    bar_sync();

    // ================= P3 =================
    short8v ac0 = *(const short8v*)(vrow);
    short8v ac1 = *(const short8v*)(vrow + 64);
#pragma unroll
    for (int n = 0; n < 4; ++n) {
      acc[n] = __builtin_amdgcn_mfma_f32_16x16x32_bf16(ac0, Bf[0][n], acc[n], 0, 0, 0);
      acc[n] = __builtin_amdgcn_mfma_f32_16x16x32_bf16(ac1, Bf[1][n], acc[n], 0, 0, 0);
    }
    const int hidx = wv * 16 + l15;
#pragma unroll
    for (int r = 0; r < 4; ++r) {
      const int row = kg * 4 + r;
      float cc = sigf(acc[1][r]) * c_reg[r] + sigf(acc[0][r]) * tanhf_fast(acc[2][r]);
      c_reg[r] = cc;
      float hn = sigf(acc[3][r]) * tanhf_fast(cc);
      float hv = hn * bf2f(sGb[p][sc][row][hidx]);   // pre-decay with gamma_h(s+1)
      sV[row][128 + hidx] = f2bf(hv);
    }
    if (sc == 3) {
      if (s + 1 < Ssz) {   // write staged chunk + ml(s+1) from regs
        const int q = p ^ 1;
        uint4 mq;
        mq.x = (unsigned)f2bf(mr0.x) | ((unsigned)f2bf(mr0.y) << 16);
        mq.y = (unsigned)f2bf(mr0.z) | ((unsigned)f2bf(mr0.w) << 16);
        mq.z = (unsigned)f2bf(mr1.x) | ((unsigned)f2bf(mr1.y) << 16);
        mq.w = (unsigned)f2bf(mr1.z) | ((unsigned)f2bf(mr1.w) << 16);
        *(float4*)&sXb[q][sg2][rg][fg8]     = xr0;
        *(float4*)&sXb[q][sg2][rg][fg8 + 4] = xr1;
        *(uint4*)&sMb[q][sg2][rg][fg8] = mq;
        *(uint4*)&sBb[q][sg2][rg][fg8] = ber;
        *(uint4*)&sGb[q][sg2][rg][hg16]     = gr0;
        *(uint4*)&sGb[q][sg2][rg][hg16 + 8] = gr1;
        if (sg2 == 0) *(uint4*)&sV[rg][64 + fg8] = mq;
      }
    } else {   // ml(s+1) from current chunk LDS
      const int row = tid >> 5, c2 = (tid & 31) * 2;
      unsigned int mm = *(const unsigned int*)&sMb[p][sc + 1][row][c2];
      *(unsigned int*)&sV[row][64 + c2] = mm;
    }
    bar_sync();
  }

  // loss reduction
  for (int off = 32; off > 0; off >>= 1) lacc += __shfl_xor(lacc, off);
  if (lane == 0) sRed[wv] = lacc;
  __syncthreads();
  if (tid == 0) {
    float tot = 0.f;
#pragma unroll
    for (int w = 0; w < 8; ++w) tot += sRed[w];
    atomicAdd(out_loss, tot * (1.0f / Ssz));
  }
}

extern "C" void kernel_launch(void* const* d_in, const int* in_sizes, int n_in,
                              void* d_out, int out_size, void* d_ws, size_t ws_size,
                              hipStream_t stream) {
  const float* x   = (const float*)d_in[0];
  const float* m   = (const float*)d_in[1];
  const float* t   = (const float*)d_in[2];
  const float* Wdh = (const float*)d_in[3];
  const float* bdh = (const float*)d_in[4];
  const float* Wdm = (const float*)d_in[5];
  const float* bdm = (const float*)d_in[6];
  const float* Wtr = (const float*)d_in[7];
  const float* btr = (const float*)d_in[8];
  const float* Wfr = (const float*)d_in[9];
  const float* bfr = (const float*)d_in[10];
  const float* Wwc = (const float*)d_in[11];
  const float* bwc = (const float*)d_in[12];
  const float* Wih = (const float*)d_in[13];
  const float* Whh = (const float*)d_in[14];
  const float* bih = (const float*)d_in[15];
  const float* bhh = (const float*)d_in[16];

  char* ws = (char*)d_ws;
  float* inv_denom = (float*)ws;                       // 2 KiB
  ushort_t* Wpk    = (ushort_t*)(ws + 2048);           // 256 KiB
  ushort_t* gh_ws  = (ushort_t*)(ws + 264192);         // 32 MiB  (B*S*128 bf16)
  ushort_t* be_ws  = (ushort_t*)(ws + 264192 + (size_t)Bsz * Ssz * 128 * 2);  // 16 MiB
  float* out_f = (float*)d_out;
  float* out_loss = out_f + (size_t)Bsz * Ssz * Fsz;

  denom_kernel<<<Ssz, 256, 0, stream>>>(m, inv_denom);
  pack_kernel<<<64, 256, 0, stream>>>(Wih, Whh, Wpk);
  gh_kernel<<<(Bsz * Ssz) / 64, 256, 0, stream>>>(t, Wdh, bdh, gh_ws);
  beta_kernel<<<(Bsz * Ssz) / 64, 256, 0, stream>>>(t, m, Wdm, bdm, Wwc, bwc, be_ws);
  hipMemsetAsync(out_loss, 0, sizeof(float), stream);
  rits_kernel<<<Bsz / GR, 512, 0, stream>>>(x, m, Wtr, btr, Wfr, bfr, bih, bhh,
                                            Wpk, inv_denom, gh_ws, be_ws, out_f, out_loss);
}